// Round 5
// baseline (717.443 us; speedup 1.0000x reference)
//
#include <hip/hip_runtime.h>
#include <float.h>

#define K_CLUST 10000
#define K_PAD   10240           // 640 k-tiles of 16
#define DIM     128
#define N_SAMP  16384
#define KSPLIT  32
#define KT_PER  20              // 640 ktiles / 32 splits
#define CAP     16              // candidate list capacity per sample
#define MARGIN2 1.5f            // 2x worst-case f16 score error each side (verified r4)

typedef _Float16 half8  __attribute__((ext_vector_type(8)));
typedef float    floatx4 __attribute__((ext_vector_type(4)));

// order-preserving float<->uint encoding for atomicMax
__device__ inline unsigned enc_f(float f) {
    unsigned u = __float_as_uint(f);
    return u ^ (((int)u >> 31) | 0x80000000u);
}
__device__ inline float dec_f(unsigned u) {
    unsigned t = (u & 0x80000000u) ? (u ^ 0x80000000u) : ~u;
    return __uint_as_float(t);
}

// ---- Kernel 1: prep. blocks [0,160): m-side (msq, mT, mh). [160,416): x-side (xh, inits).
__global__ __launch_bounds__(256) void prep_kernel(
        const float* __restrict__ m, const float* __restrict__ x,
        float* __restrict__ msq, float* __restrict__ mT,
        _Float16* __restrict__ mh, _Float16* __restrict__ xh,
        unsigned* __restrict__ smax, int* __restrict__ cnt,
        float* __restrict__ diff_out) {
    __shared__ float tile[64][DIM + 1];
    __shared__ float psum[64][4];
    const int b = blockIdx.x, tid = threadIdx.x;

    if (b < 160) {                              // ---- m part: k0 = b*64
        const int k0 = b * 64;
        const int kl = tid & 63, dg = tid >> 6;
        const int k = k0 + kl;
        float ss = 0.f;
        #pragma unroll 4
        for (int dd = 0; dd < 32; ++dd) {
            int d = dg * 32 + dd;
            float v = (k < K_CLUST) ? m[(size_t)d * K_CLUST + k] : 0.f;
            tile[kl][d] = v;
            ss = fmaf(v, v, ss);
        }
        psum[kl][dg] = ss;
        __syncthreads();
        if (dg == 0)
            msq[k] = (k < K_CLUST) ? (psum[kl][0] + psum[kl][1] + psum[kl][2] + psum[kl][3])
                                   : -1e30f;    // pad never wins
        // mh: [k/16][d/8][k%16][d%8] f16, 16B chunks
        #pragma unroll
        for (int p = 0; p < 4; ++p) {
            int c = tid + p * 256;              // 0..1023
            int kt = c >> 8, dgc = (c >> 4) & 15, k16 = c & 15;
            half8 hv;
            #pragma unroll
            for (int j = 0; j < 8; ++j) hv[j] = (_Float16)tile[kt * 16 + k16][dgc * 8 + j];
            size_t ci = ((size_t)(b * 4 + kt) * 16 + dgc) * 16 + k16;
            ((half8*)mh)[ci] = hv;
        }
        // mT [K,DIM] fp32 for rescue/quant gather
        const int r = tid >> 2, p2 = tid & 3;
        if (k0 + r < K_CLUST) {
            float4* dst = (float4*)(mT + (size_t)(k0 + r) * DIM + p2 * 32);
            #pragma unroll
            for (int j = 0; j < 8; ++j) {
                float4 v;
                v.x = tile[r][p2 * 32 + 4 * j + 0];
                v.y = tile[r][p2 * 32 + 4 * j + 1];
                v.z = tile[r][p2 * 32 + 4 * j + 2];
                v.w = tile[r][p2 * 32 + 4 * j + 3];
                dst[j] = v;
            }
        }
    } else {                                    // ---- x part: s0 = (b-160)*64
        const int s0 = (b - 160) * 64;
        const float4* xg = (const float4*)(x + (size_t)s0 * DIM);
        #pragma unroll
        for (int i = 0; i < 8; ++i) {
            int fi = tid + i * 256;             // 0..2047
            int sl = fi >> 5, d4 = fi & 31;
            float4 v = xg[fi];
            tile[sl][d4 * 4 + 0] = v.x; tile[sl][d4 * 4 + 1] = v.y;
            tile[sl][d4 * 4 + 2] = v.z; tile[sl][d4 * 4 + 3] = v.w;
        }
        __syncthreads();
        // xh: [s/16][d/8][s%16][d%8]
        #pragma unroll
        for (int p = 0; p < 4; ++p) {
            int c = tid + p * 256;
            int st = c >> 8, dgc = (c >> 4) & 15, ml = c & 15;
            half8 hv;
            #pragma unroll
            for (int j = 0; j < 8; ++j) hv[j] = (_Float16)tile[st * 16 + ml][dgc * 8 + j];
            size_t ci = ((size_t)(s0 / 16 + st) * 16 + dgc) * 16 + ml;
            ((half8*)xh)[ci] = hv;
        }
        if (tid < 64) { smax[s0 + tid] = 0u; cnt[s0 + tid] = 0; }
        if (b == 160 && tid == 0) *diff_out = 0.f;
    }
}

// ---- Kernel 2/3: f16 MFMA score pass. COLLECT=false: per-sample max (atomicMax).
//      COLLECT=true: gather candidates with score >= max - MARGIN2.
// Wave owns 64 samples (4 tiles); block's 4 waves share the k-range (B-frags L1-hot).
// KSPLIT=32 -> 2048 blocks -> 8 waves/SIMD; launch_bounds(256,8) pins VGPR<=64.
template <bool COLLECT>
__global__ __launch_bounds__(256, 8) void score_kernel(
        const _Float16* __restrict__ xh, const _Float16* __restrict__ mh,
        const float* __restrict__ msq, unsigned* __restrict__ smax,
        int* __restrict__ cnt, int* __restrict__ cand) {
    const int tid = threadIdx.x;
    const int wv = tid >> 6, lane = tid & 63;
    const int n = lane & 15, quad = lane >> 4;
    const int ks = blockIdx.x & (KSPLIT - 1);
    const int grp = blockIdx.x / KSPLIT;
    const int stile0 = (grp * 4 + wv) * 4;      // 4 sample-tiles per wave
    const int kt0 = ks * KT_PER;

    const half8* xf = (const half8*)xh;
    const half8* mf = (const half8*)mh;

    // A-frags resident across the whole k-loop: 16 x half8 = 64 VGPRs
    half8 a[4][4];
    #pragma unroll
    for (int ii = 0; ii < 4; ++ii)
        #pragma unroll
        for (int t = 0; t < 4; ++t)
            a[ii][t] = xf[((size_t)(stile0 + ii) * 16 + t * 4 + quad) * 16 + n];

    float rmax[4][4];
    float thr[4][4];
    #pragma unroll
    for (int ii = 0; ii < 4; ++ii)
        #pragma unroll
        for (int r = 0; r < 4; ++r) {
            rmax[ii][r] = -FLT_MAX;
            if (COLLECT)
                thr[ii][r] = dec_f(smax[(stile0 + ii) * 16 + quad * 4 + r]) - MARGIN2;
        }

    for (int kt = kt0; kt < kt0 + KT_PER; ++kt) {
        half8 bfr[4];
        #pragma unroll
        for (int t = 0; t < 4; ++t)
            bfr[t] = mf[((size_t)kt * 16 + t * 4 + quad) * 16 + n];
        float mq = msq[kt * 16 + n];
        #pragma unroll
        for (int ii = 0; ii < 4; ++ii) {
            floatx4 c = {0.f, 0.f, 0.f, 0.f};
            #pragma unroll
            for (int t = 0; t < 4; ++t)
                c = __builtin_amdgcn_mfma_f32_16x16x32_f16(a[ii][t], bfr[t], c, 0, 0, 0);
            #pragma unroll
            for (int r = 0; r < 4; ++r) {
                float sc = fmaf(-2.f, c[r], mq);    // score for (row=quad*4+r, col k=kt*16+n)
                if (!COLLECT) {
                    rmax[ii][r] = fmaxf(rmax[ii][r], sc);
                } else if (sc >= thr[ii][r]) {
                    int sample = (stile0 + ii) * 16 + quad * 4 + r;
                    int slot = atomicAdd(&cnt[sample], 1);
                    if (slot < CAP) cand[sample * CAP + slot] = kt * 16 + n;
                }
            }
        }
    }

    if (!COLLECT) {
        #pragma unroll
        for (int ii = 0; ii < 4; ++ii)
            #pragma unroll
            for (int r = 0; r < 4; ++r) {
                float v = rmax[ii][r];
                #pragma unroll
                for (int mk = 1; mk <= 8; mk <<= 1)
                    v = fmaxf(v, __shfl_xor(v, mk));    // reduce over n within quad
                if (n == 0)
                    atomicMax(&smax[(stile0 + ii) * 16 + quad * 4 + r], enc_f(v));
            }
    }
}

// ---- Kernel 4: fused exact fp32 rescue + quantize + MSE. One wave per sample.
__global__ __launch_bounds__(256) void rescue_quant_kernel(
        const float* __restrict__ x, const float* __restrict__ mT,
        const float* __restrict__ msq, const int* __restrict__ cnt,
        const int* __restrict__ cand, float* __restrict__ qout,
        float* __restrict__ idx_f, float* __restrict__ diff_out) {
    const int wv = threadIdx.x >> 6, lane = threadIdx.x & 63;
    const int s = blockIdx.x * 4 + wv;
    const float2 xx = ((const float2*)x)[(size_t)s * 64 + lane];
    const int c = cnt[s];
    float best = -FLT_MAX; int bk = 0x7fffffff;
    if (c <= CAP) {
        for (int i = 0; i < c; ++i) {
            int k = cand[s * CAP + i];
            float2 mm = ((const float2*)mT)[(size_t)k * 64 + lane];
            float p = xx.x * mm.x + xx.y * mm.y;
            #pragma unroll
            for (int off = 32; off; off >>= 1) p += __shfl_xor(p, off);
            float sc = msq[k] - 2.f * p;            // identical in all lanes
            if (sc > best || (sc == best && k < bk)) { best = sc; bk = k; }
        }
    } else {                                    // overflow: exact full scan (never expected)
        for (int k = 0; k < K_CLUST; ++k) {
            float2 mm = ((const float2*)mT)[(size_t)k * 64 + lane];
            float p = xx.x * mm.x + xx.y * mm.y;
            #pragma unroll
            for (int off = 32; off; off >>= 1) p += __shfl_xor(p, off);
            float sc = msq[k] - 2.f * p;
            if (sc > best) { best = sc; bk = k; }   // ascending k: '>' keeps lowest
        }
    }
    if (bk == 0x7fffffff) bk = 0;               // safety: never expected (cnt >= 1)
    if (lane == 0) idx_f[s] = (float)bk;
    // quantize row (bk identical across the wave; float2-coalesced), MSE partial
    float2 q = ((const float2*)mT)[(size_t)bk * 64 + lane];
    ((float2*)qout)[(size_t)s * 64 + lane] = q;
    float ax = xx.x - q.x, ay = xx.y - q.y;
    float dd = ax * ax + ay * ay;
    #pragma unroll
    for (int off = 32; off; off >>= 1) dd += __shfl_xor(dd, off);
    __shared__ float wsum[4];
    if (lane == 0) wsum[wv] = dd;
    __syncthreads();
    if (threadIdx.x == 0) {
        float t = wsum[0] + wsum[1] + wsum[2] + wsum[3];
        atomicAdd(diff_out, t * (1.0f / ((float)N_SAMP * (float)DIM)));
    }
}

extern "C" void kernel_launch(void* const* d_in, const int* in_sizes, int n_in,
                              void* d_out, int out_size, void* d_ws, size_t ws_size,
                              hipStream_t stream) {
    const float* x = (const float*)d_in[0];          // [16,32,32,128]
    const float* m = (const float*)d_in[1];          // [128,10000]
    float* out    = (float*)d_out;
    float* quant  = out;                                  // 2,097,152 f
    float* idx_f  = out + (size_t)N_SAMP * DIM;           // 16,384 f
    float* diff   = out + (size_t)N_SAMP * DIM + N_SAMP;  // 1 f

    char* ws = (char*)d_ws;                  // ~13.2 MB total
    float*     msq  = (float*)    (ws);                       // 10240 f  (40,960 B)
    float*     mT   = (float*)    (ws + 40960);               // 10000*128 f (5,120,000 B)
    _Float16*  mh   = (_Float16*) (ws + 5160960);             // 10240*128 h (2,621,440 B)
    _Float16*  xh   = (_Float16*) (ws + 7782400);             // 16384*128 h (4,194,304 B)
    unsigned*  smax = (unsigned*) (ws + 11976704);            // 16384 u
    int*       cnt  = (int*)      (ws + 12042240);            // 16384 i
    int*       cand = (int*)      (ws + 12107776);            // 16384*CAP i (1,048,576 B)

    prep_kernel<<<416, 256, 0, stream>>>(m, x, msq, mT, mh, xh, smax, cnt, diff);
    score_kernel<false><<<64 * KSPLIT, 256, 0, stream>>>(xh, mh, msq, smax, cnt, cand);
    score_kernel<true><<<64 * KSPLIT, 256, 0, stream>>>(xh, mh, msq, smax, cnt, cand);
    rescue_quant_kernel<<<N_SAMP / 4, 256, 0, stream>>>(x, mT, msq, cnt, cand,
                                                        quant, idx_f, diff);
}

// Round 6
// 231.644 us; speedup vs baseline: 3.0972x; 3.0972x over previous
//
#include <hip/hip_runtime.h>
#include <float.h>

#define K_CLUST 10000
#define K_PAD   10240           // 640 k-tiles of 16
#define DIM     128
#define N_SAMP  16384
#define KSPLIT  32
#define KT_PER  20              // 640 ktiles / 32 splits
#define CAP     16              // candidate list capacity per sample
#define MARGIN2 1.5f            // 2x worst-case f16 score error each side (verified r4)

typedef _Float16 half8  __attribute__((ext_vector_type(8)));
typedef float    floatx4 __attribute__((ext_vector_type(4)));

// order-preserving float<->uint encoding for atomicMax
__device__ inline unsigned enc_f(float f) {
    unsigned u = __float_as_uint(f);
    return u ^ (((int)u >> 31) | 0x80000000u);
}
__device__ inline float dec_f(unsigned u) {
    unsigned t = (u & 0x80000000u) ? (u ^ 0x80000000u) : ~u;
    return __uint_as_float(t);
}

// ---- Kernel 1: prep. blocks [0,160): m-side (msq, mT, mh). [160,416): x-side (xh, inits).
__global__ __launch_bounds__(256) void prep_kernel(
        const float* __restrict__ m, const float* __restrict__ x,
        float* __restrict__ msq, float* __restrict__ mT,
        _Float16* __restrict__ mh, _Float16* __restrict__ xh,
        unsigned* __restrict__ smax, int* __restrict__ cnt,
        float* __restrict__ diff_out) {
    __shared__ float tile[64][DIM + 1];
    __shared__ float psum[64][4];
    const int b = blockIdx.x, tid = threadIdx.x;

    if (b < 160) {                              // ---- m part: k0 = b*64
        const int k0 = b * 64;
        const int kl = tid & 63, dg = tid >> 6;
        const int k = k0 + kl;
        float ss = 0.f;
        #pragma unroll 4
        for (int dd = 0; dd < 32; ++dd) {
            int d = dg * 32 + dd;
            float v = (k < K_CLUST) ? m[(size_t)d * K_CLUST + k] : 0.f;
            tile[kl][d] = v;
            ss = fmaf(v, v, ss);
        }
        psum[kl][dg] = ss;
        __syncthreads();
        if (dg == 0)
            msq[k] = (k < K_CLUST) ? (psum[kl][0] + psum[kl][1] + psum[kl][2] + psum[kl][3])
                                   : -1e30f;    // pad never wins
        // mh: [k/16][d/8][k%16][d%8] f16, 16B chunks
        #pragma unroll
        for (int p = 0; p < 4; ++p) {
            int c = tid + p * 256;              // 0..1023
            int kt = c >> 8, dgc = (c >> 4) & 15, k16 = c & 15;
            half8 hv;
            #pragma unroll
            for (int j = 0; j < 8; ++j) hv[j] = (_Float16)tile[kt * 16 + k16][dgc * 8 + j];
            size_t ci = ((size_t)(b * 4 + kt) * 16 + dgc) * 16 + k16;
            ((half8*)mh)[ci] = hv;
        }
        // mT [K,DIM] fp32 for rescue/quant gather
        const int r = tid >> 2, p2 = tid & 3;
        if (k0 + r < K_CLUST) {
            float4* dst = (float4*)(mT + (size_t)(k0 + r) * DIM + p2 * 32);
            #pragma unroll
            for (int j = 0; j < 8; ++j) {
                float4 v;
                v.x = tile[r][p2 * 32 + 4 * j + 0];
                v.y = tile[r][p2 * 32 + 4 * j + 1];
                v.z = tile[r][p2 * 32 + 4 * j + 2];
                v.w = tile[r][p2 * 32 + 4 * j + 3];
                dst[j] = v;
            }
        }
    } else {                                    // ---- x part: s0 = (b-160)*64
        const int s0 = (b - 160) * 64;
        const float4* xg = (const float4*)(x + (size_t)s0 * DIM);
        #pragma unroll
        for (int i = 0; i < 8; ++i) {
            int fi = tid + i * 256;             // 0..2047
            int sl = fi >> 5, d4 = fi & 31;
            float4 v = xg[fi];
            tile[sl][d4 * 4 + 0] = v.x; tile[sl][d4 * 4 + 1] = v.y;
            tile[sl][d4 * 4 + 2] = v.z; tile[sl][d4 * 4 + 3] = v.w;
        }
        __syncthreads();
        // xh: [s/16][d/8][s%16][d%8]
        #pragma unroll
        for (int p = 0; p < 4; ++p) {
            int c = tid + p * 256;
            int st = c >> 8, dgc = (c >> 4) & 15, ml = c & 15;
            half8 hv;
            #pragma unroll
            for (int j = 0; j < 8; ++j) hv[j] = (_Float16)tile[st * 16 + ml][dgc * 8 + j];
            size_t ci = ((size_t)(s0 / 16 + st) * 16 + dgc) * 16 + ml;
            ((half8*)xh)[ci] = hv;
        }
        if (tid < 64) { smax[s0 + tid] = 0u; cnt[s0 + tid] = 0; }
        if (b == 160 && tid == 0) *diff_out = 0.f;
    }
}

// ---- Kernel 2/3: f16 MFMA score pass. COLLECT=false: per-sample max (atomicMax).
//      COLLECT=true: gather candidates with score >= max - MARGIN2.
// Wave owns 64 samples (4 tiles); block's 4 waves share the k-range (B-frags L1-hot).
// KSPLIT=32 -> 2048 blocks -> 8 waves/SIMD by grid. VGPR=64 (r4-measured) already
// permits 8 waves/SIMD -- do NOT cap registers below that (r5: min-waves=8 forced
// VGPR 32 and spilled the 64-VGPR A-tile to scratch, 1.1 GB HBM traffic, 3.4x slower).
template <bool COLLECT>
__global__ __launch_bounds__(256, 4) void score_kernel(
        const _Float16* __restrict__ xh, const _Float16* __restrict__ mh,
        const float* __restrict__ msq, unsigned* __restrict__ smax,
        int* __restrict__ cnt, int* __restrict__ cand) {
    const int tid = threadIdx.x;
    const int wv = tid >> 6, lane = tid & 63;
    const int n = lane & 15, quad = lane >> 4;
    const int ks = blockIdx.x & (KSPLIT - 1);
    const int grp = blockIdx.x / KSPLIT;
    const int stile0 = (grp * 4 + wv) * 4;      // 4 sample-tiles per wave
    const int kt0 = ks * KT_PER;

    const half8* xf = (const half8*)xh;
    const half8* mf = (const half8*)mh;

    // A-frags resident across the whole k-loop: 16 x half8 = 64 VGPRs
    half8 a[4][4];
    #pragma unroll
    for (int ii = 0; ii < 4; ++ii)
        #pragma unroll
        for (int t = 0; t < 4; ++t)
            a[ii][t] = xf[((size_t)(stile0 + ii) * 16 + t * 4 + quad) * 16 + n];

    float rmax[4][4];
    float thr[4][4];
    #pragma unroll
    for (int ii = 0; ii < 4; ++ii)
        #pragma unroll
        for (int r = 0; r < 4; ++r) {
            rmax[ii][r] = -FLT_MAX;
            if (COLLECT)
                thr[ii][r] = dec_f(smax[(stile0 + ii) * 16 + quad * 4 + r]) - MARGIN2;
        }

    for (int kt = kt0; kt < kt0 + KT_PER; ++kt) {
        half8 bfr[4];
        #pragma unroll
        for (int t = 0; t < 4; ++t)
            bfr[t] = mf[((size_t)kt * 16 + t * 4 + quad) * 16 + n];
        float mq = msq[kt * 16 + n];
        #pragma unroll
        for (int ii = 0; ii < 4; ++ii) {
            floatx4 c = {0.f, 0.f, 0.f, 0.f};
            #pragma unroll
            for (int t = 0; t < 4; ++t)
                c = __builtin_amdgcn_mfma_f32_16x16x32_f16(a[ii][t], bfr[t], c, 0, 0, 0);
            #pragma unroll
            for (int r = 0; r < 4; ++r) {
                float sc = fmaf(-2.f, c[r], mq);    // score for (row=quad*4+r, col k=kt*16+n)
                if (!COLLECT) {
                    rmax[ii][r] = fmaxf(rmax[ii][r], sc);
                } else if (sc >= thr[ii][r]) {
                    int sample = (stile0 + ii) * 16 + quad * 4 + r;
                    int slot = atomicAdd(&cnt[sample], 1);
                    if (slot < CAP) cand[sample * CAP + slot] = kt * 16 + n;
                }
            }
        }
    }

    if (!COLLECT) {
        #pragma unroll
        for (int ii = 0; ii < 4; ++ii)
            #pragma unroll
            for (int r = 0; r < 4; ++r) {
                float v = rmax[ii][r];
                #pragma unroll
                for (int mk = 1; mk <= 8; mk <<= 1)
                    v = fmaxf(v, __shfl_xor(v, mk));    // reduce over n within quad
                if (n == 0)
                    atomicMax(&smax[(stile0 + ii) * 16 + quad * 4 + r], enc_f(v));
            }
    }
}

// ---- Kernel 4: fused exact fp32 rescue + quantize + MSE. One wave per sample.
__global__ __launch_bounds__(256) void rescue_quant_kernel(
        const float* __restrict__ x, const float* __restrict__ mT,
        const float* __restrict__ msq, const int* __restrict__ cnt,
        const int* __restrict__ cand, float* __restrict__ qout,
        float* __restrict__ idx_f, float* __restrict__ diff_out) {
    const int wv = threadIdx.x >> 6, lane = threadIdx.x & 63;
    const int s = blockIdx.x * 4 + wv;
    const float2 xx = ((const float2*)x)[(size_t)s * 64 + lane];
    const int c = cnt[s];
    float best = -FLT_MAX; int bk = 0x7fffffff;
    if (c <= CAP) {
        for (int i = 0; i < c; ++i) {
            int k = cand[s * CAP + i];
            float2 mm = ((const float2*)mT)[(size_t)k * 64 + lane];
            float p = xx.x * mm.x + xx.y * mm.y;
            #pragma unroll
            for (int off = 32; off; off >>= 1) p += __shfl_xor(p, off);
            float sc = msq[k] - 2.f * p;            // identical in all lanes
            if (sc > best || (sc == best && k < bk)) { best = sc; bk = k; }
        }
    } else {                                    // overflow: exact full scan (never expected)
        for (int k = 0; k < K_CLUST; ++k) {
            float2 mm = ((const float2*)mT)[(size_t)k * 64 + lane];
            float p = xx.x * mm.x + xx.y * mm.y;
            #pragma unroll
            for (int off = 32; off; off >>= 1) p += __shfl_xor(p, off);
            float sc = msq[k] - 2.f * p;
            if (sc > best) { best = sc; bk = k; }   // ascending k: '>' keeps lowest
        }
    }
    if (bk == 0x7fffffff) bk = 0;               // safety: never expected (cnt >= 1)
    if (lane == 0) idx_f[s] = (float)bk;
    // quantize row (bk identical across the wave; float2-coalesced), MSE partial
    float2 q = ((const float2*)mT)[(size_t)bk * 64 + lane];
    ((float2*)qout)[(size_t)s * 64 + lane] = q;
    float ax = xx.x - q.x, ay = xx.y - q.y;
    float dd = ax * ax + ay * ay;
    #pragma unroll
    for (int off = 32; off; off >>= 1) dd += __shfl_xor(dd, off);
    __shared__ float wsum[4];
    if (lane == 0) wsum[wv] = dd;
    __syncthreads();
    if (threadIdx.x == 0) {
        float t = wsum[0] + wsum[1] + wsum[2] + wsum[3];
        atomicAdd(diff_out, t * (1.0f / ((float)N_SAMP * (float)DIM)));
    }
}

extern "C" void kernel_launch(void* const* d_in, const int* in_sizes, int n_in,
                              void* d_out, int out_size, void* d_ws, size_t ws_size,
                              hipStream_t stream) {
    const float* x = (const float*)d_in[0];          // [16,32,32,128]
    const float* m = (const float*)d_in[1];          // [128,10000]
    float* out    = (float*)d_out;
    float* quant  = out;                                  // 2,097,152 f
    float* idx_f  = out + (size_t)N_SAMP * DIM;           // 16,384 f
    float* diff   = out + (size_t)N_SAMP * DIM + N_SAMP;  // 1 f

    char* ws = (char*)d_ws;                  // ~13.2 MB total
    float*     msq  = (float*)    (ws);                       // 10240 f  (40,960 B)
    float*     mT   = (float*)    (ws + 40960);               // 10000*128 f (5,120,000 B)
    _Float16*  mh   = (_Float16*) (ws + 5160960);             // 10240*128 h (2,621,440 B)
    _Float16*  xh   = (_Float16*) (ws + 7782400);             // 16384*128 h (4,194,304 B)
    unsigned*  smax = (unsigned*) (ws + 11976704);            // 16384 u
    int*       cnt  = (int*)      (ws + 12042240);            // 16384 i
    int*       cand = (int*)      (ws + 12107776);            // 16384*CAP i (1,048,576 B)

    prep_kernel<<<416, 256, 0, stream>>>(m, x, msq, mT, mh, xh, smax, cnt, diff);
    score_kernel<false><<<64 * KSPLIT, 256, 0, stream>>>(xh, mh, msq, smax, cnt, cand);
    score_kernel<true><<<64 * KSPLIT, 256, 0, stream>>>(xh, mh, msq, smax, cnt, cand);
    rescue_quant_kernel<<<N_SAMP / 4, 256, 0, stream>>>(x, mT, msq, cnt, cand,
                                                        quant, idx_f, diff);
}